// Round 2
// baseline (1438.061 us; speedup 1.0000x reference)
//
#include <hip/hip_runtime.h>
#include <hip/hip_bf16.h>
#include <cstdint>
#include <cstddef>

// ---------------- JAX threefry2x32 (partitionable scheme) — FROZEN (verified R1)
struct TF2 { uint32_t a, b; };

__host__ __device__ constexpr uint32_t rotl32(uint32_t v, int r) {
  return (v << r) | (v >> (32 - r));
}

__host__ __device__ constexpr TF2 threefry2x32(uint32_t k0, uint32_t k1,
                                               uint32_t x0, uint32_t x1) {
  uint32_t ks0 = k0, ks1 = k1, ks2 = k0 ^ k1 ^ 0x1BD11BDAu;
  const int rotA[4] = {13, 15, 26, 6};
  const int rotB[4] = {17, 29, 16, 24};
  x0 += ks0; x1 += ks1;
  for (int i = 0; i < 5; ++i) {
    const int* rot = (i % 2 == 0) ? rotA : rotB;
    for (int j = 0; j < 4; ++j) {
      x0 += x1; x1 = rotl32(x1, rot[j]); x1 ^= x0;
    }
    uint32_t ks[3] = {ks0, ks1, ks2};
    x0 += ks[(i + 1) % 3];
    x1 += ks[(i + 2) % 3] + (uint32_t)(i + 1);
  }
  return TF2{x0, x1};
}

__device__ __forceinline__ float jax_mask(uint32_t child, uint32_t idx) {
  TF2 ck = threefry2x32(0u, 42u, 0u, child);   // constant-folds
  TF2 r  = threefry2x32(ck.a, ck.b, 0u, idx);
  uint32_t bits = r.a ^ r.b;
  float u = __uint_as_float((bits >> 9) | 0x3f800000u) - 1.0f;
  return (u < 0.7f) ? (1.0f / 0.7f) : 0.0f;
}

__device__ __forceinline__ unsigned short f2bf(float f) {
  uint32_t u = __float_as_uint(f);
  uint32_t r = (u + 0x7fffu + ((u >> 16) & 1u)) >> 16;   // RNE
  return (unsigned short)r;
}

__device__ __forceinline__ float bf2f(unsigned short b) {
  return __uint_as_float((uint32_t)b << 16);
}

typedef __attribute__((ext_vector_type(8))) short short8;
typedef __attribute__((ext_vector_type(4))) float f32x4;

// async global->LDS, 16B per lane. LDS dest = wave-uniform base + lane*16.
__device__ __forceinline__ void async_copy16(const unsigned short* g, unsigned short* l) {
  __builtin_amdgcn_global_load_lds(
      (const __attribute__((address_space(1))) unsigned int*)g,
      (__attribute__((address_space(3))) unsigned int*)l, 16, 0, 0);
}

// ---------------- build x (bf16) = [image_emb ; emb_table[targets]*word_mask]
__global__ __launch_bounds__(256) void build_x_kernel(
    const float* __restrict__ img, const int* __restrict__ tgt,
    const float* __restrict__ emb, unsigned short* __restrict__ x) {
  const int idx = blockIdx.x * 256 + threadIdx.x;   // b*32768 + t*512 + e
  const int e = idx & 511;
  const int t = (idx >> 9) & 63;
  const int b = idx >> 15;
  float v;
  if (t == 0) {
    v = img[b * 512 + e];
  } else {
    const int w = tgt[b * 64 + (t - 1)];
    const float wm = jax_mask(0u, (uint32_t)(b * 512 + e));
    v = emb[(size_t)w * 512 + e] * wm;
  }
  x[idx] = f2bf(v);
}

// ---------------- transpose W_rec (512x2048) -> WT (2048x512) fp32 -------
__global__ __launch_bounds__(256) void transpose_wrec(
    const float* __restrict__ in, float* __restrict__ out) {
  __shared__ float tile[32][33];
  const int j0 = blockIdx.x * 32;
  const int u0 = blockIdx.y * 32;
  const int tx = threadIdx.x & 31;
  const int ty = threadIdx.x >> 5;
  for (int r = ty; r < 32; r += 8)
    tile[r][tx] = in[(size_t)(u0 + r) * 2048 + (j0 + tx)];
  __syncthreads();
  for (int r = ty; r < 32; r += 8)
    out[(size_t)(j0 + r) * 512 + (u0 + tx)] = tile[tx][r];
}

// ------- transpose+convert fp32 [R][C] -> bf16 [C][R]  (R=512 here) ------
__global__ __launch_bounds__(256) void transpose_cvt(
    const float* __restrict__ in, unsigned short* __restrict__ out,
    int R, int C) {
  __shared__ float tile[32][33];
  const int c0 = blockIdx.x * 32;
  const int r0 = blockIdx.y * 32;
  const int tx = threadIdx.x & 31;
  const int ty = threadIdx.x >> 5;
  for (int r = ty; r < 32; r += 8)
    tile[r][tx] = in[(size_t)(r0 + r) * C + (c0 + tx)];
  __syncthreads();
  for (int r = ty; r < 32; r += 8)
    out[(size_t)(c0 + r) * R + (r0 + tx)] = f2bf(tile[tx][r]);
}

// ---------------- bf16 MFMA GEMM: C[M][N] = A[M][512] * BT[N][512]^T + bias
// 128x128 tile, BK=32, 16x16x32 MFMA, fp32 accum. m97 structure.
__global__ __launch_bounds__(256) void gemm_bf16_mfma(
    const unsigned short* __restrict__ A, const unsigned short* __restrict__ BT,
    const float* __restrict__ bias, float* __restrict__ C, int M, int N) {
  __shared__ unsigned short As[128 * 32];   // [m][k] rows of 32 bf16 (64B)
  __shared__ unsigned short Bs[128 * 32];   // [n][k]
  const int tid = threadIdx.x;
  const int lane = tid & 63;
  const int wave = tid >> 6;              // 0..3
  const int wm = (wave >> 1) * 64;
  const int wn = (wave & 1) * 64;
  const int m0 = blockIdx.y * 128;
  const int n0 = blockIdx.x * 128;

  f32x4 zero4 = {0.f, 0.f, 0.f, 0.f};
  f32x4 acc[4][4];
#pragma unroll
  for (int i = 0; i < 4; ++i)
#pragma unroll
    for (int j = 0; j < 4; ++j) acc[i][j] = zero4;

  // staging: thread covers row tid/4 (and +64), 16B chunk tid%4
  const unsigned short* ga = A + (size_t)(m0 + (tid >> 2)) * 512 + (tid & 3) * 8;
  const unsigned short* gb = BT + (size_t)(n0 + (tid >> 2)) * 512 + (tid & 3) * 8;
  unsigned short* lwA = As + wave * 512;   // + lane*16B by HW
  unsigned short* lwB = Bs + wave * 512;

  const int fr = lane & 15;
  const int kc = (lane >> 4) * 8;

  for (int k0 = 0; k0 < 512; k0 += 32) {
    __syncthreads();   // previous frag reads done before overwrite
    async_copy16(ga + k0, lwA);
    async_copy16(ga + k0 + 64 * 512, lwA + 2048);
    async_copy16(gb + k0, lwB);
    async_copy16(gb + k0 + 64 * 512, lwB + 2048);
    __syncthreads();   // drain vmcnt: LDS tiles ready

    short8 af[4], bf[4];
#pragma unroll
    for (int i = 0; i < 4; ++i)
      af[i] = *(const short8*)(As + (wm + i * 16 + fr) * 32 + kc);
#pragma unroll
    for (int i = 0; i < 4; ++i)
      bf[i] = *(const short8*)(Bs + (wn + i * 16 + fr) * 32 + kc);
#pragma unroll
    for (int mi = 0; mi < 4; ++mi)
#pragma unroll
      for (int ni = 0; ni < 4; ++ni)
        acc[mi][ni] = __builtin_amdgcn_mfma_f32_16x16x32_bf16(
            af[mi], bf[ni], acc[mi][ni], 0, 0, 0);
  }

  // epilogue: C row = quad*4+reg, col = lane&15 (m89-verified layout)
#pragma unroll
  for (int mi = 0; mi < 4; ++mi) {
    const int mrow = m0 + wm + mi * 16 + (lane >> 4) * 4;
#pragma unroll
    for (int ni = 0; ni < 4; ++ni) {
      const int ncol = n0 + wn + ni * 16 + (lane & 15);
      const float bs = bias[ncol];
#pragma unroll
      for (int r2 = 0; r2 < 4; ++r2)
        C[(size_t)(mrow + r2) * N + ncol] = acc[mi][ni][r2] + bs;
    }
  }
}

// ---------------- fused LSTM scan: ONE persistent kernel, 64 steps -------
// 32 blocks x 256 threads (1 block/CU => trivially co-resident).
// Block owns u-slice of 16; wave = gate. W_rec fragments (bf16 hi+lo) live
// in registers for the entire scan. Recurrent matmul: 3-product bf16 split
// (Ah*Wh + Ah*Wl + Al*Wh) ~= fp32. h propagates via double-buffered
// masked-h (hi/lo bf16) in global (L2/L3), hand-rolled grid barrier/step.
#define HM_PSTRIDE (2 * 4 * 32 * 512)    // per-parity ushorts: [split][gate][b][k]
#define NBLK 32

__device__ __forceinline__ void grid_barrier(unsigned int* bar, unsigned int target) {
  __syncthreads();
  __threadfence();                                   // release hm writes (wb L2)
  if (threadIdx.x == 0) {
    __hip_atomic_fetch_add(bar, 1u, __ATOMIC_RELAXED, __HIP_MEMORY_SCOPE_AGENT);
    while (__hip_atomic_load(bar, __ATOMIC_RELAXED, __HIP_MEMORY_SCOPE_AGENT) < target)
      __builtin_amdgcn_s_sleep(1);
  }
  __syncthreads();
  __threadfence();                                   // acquire: inv stale L1/L2
}

__global__ __launch_bounds__(256, 1) void lstm_coop(
    const float* __restrict__ zin, const float* __restrict__ WT,
    unsigned short* __restrict__ hm, unsigned short* __restrict__ rnn,
    unsigned int* __restrict__ bar) {
  __shared__ float zsh[4][32][17];
  const int tid = threadIdx.x;
  const int lane = tid & 63;
  const int g = tid >> 6;                 // wave index = gate (i,f,c,o)
  const int u0 = blockIdx.x * 16;
  const int fr = lane & 15;
  const int kq = (lane >> 4) * 8;

  // ---- one-time: W fragments (bf16 hi/lo) into registers ----------------
  // B-frag for 16x16x32: lane holds BT[col = fr][k = kk*32 + kq .. +8]
  short8 whi[16], wlo[16];
  {
    const float* wrow = WT + (size_t)(g * 512 + u0 + fr) * 512 + kq;
#pragma unroll
    for (int kk = 0; kk < 16; ++kk) {
      const float4 w0 = *(const float4*)(wrow + kk * 32);
      const float4 w1 = *(const float4*)(wrow + kk * 32 + 4);
      const float wv[8] = {w0.x, w0.y, w0.z, w0.w, w1.x, w1.y, w1.z, w1.w};
      short8 h8, l8;
#pragma unroll
      for (int e = 0; e < 8; ++e) {
        const unsigned short hb = f2bf(wv[e]);
        h8[e] = (short)hb;
        l8[e] = (short)f2bf(wv[e] - bf2f(hb));
      }
      whi[kk] = h8; wlo[kk] = l8;
    }
  }

  // ---- per-thread activation-phase constants ----------------------------
  const int ab = tid >> 4;            // batch (cell0); cell1 = ab+16
  const int uc = tid & 15;
  const int au = u0 + uc;             // global u for this thread's cells
  float rmask[2][4];
#pragma unroll
  for (int cc = 0; cc < 2; ++cc)
#pragma unroll
    for (int gg = 0; gg < 4; ++gg)
      rmask[cc][gg] = jax_mask(1u, (uint32_t)((gg * 32 + ab + cc * 16) * 512 + au));
  float c0 = 0.f, c1 = 0.f;

  for (int t = 0; t < 64; ++t) {
    const int rp = t & 1;             // read parity (t=0 skips reads)
    f32x4 ahh0 = {0,0,0,0}, ahl0 = {0,0,0,0}, alh0 = {0,0,0,0};
    f32x4 ahh1 = {0,0,0,0}, ahl1 = {0,0,0,0}, alh1 = {0,0,0,0};

    if (t) {
      const unsigned short* hb  = hm + (size_t)rp * HM_PSTRIDE;
      const unsigned short* hhi = hb + (size_t)((0 * 4 + g) * 32) * 512;
      const unsigned short* hlo = hb + (size_t)((1 * 4 + g) * 32) * 512;
#pragma unroll
      for (int kk = 0; kk < 16; ++kk) {
        const int ko = kk * 32 + kq;
        const short8 ah0 = *(const short8*)(hhi + (size_t)(fr) * 512 + ko);
        const short8 ah1 = *(const short8*)(hhi + (size_t)(16 + fr) * 512 + ko);
        const short8 al0 = *(const short8*)(hlo + (size_t)(fr) * 512 + ko);
        const short8 al1 = *(const short8*)(hlo + (size_t)(16 + fr) * 512 + ko);
        ahh0 = __builtin_amdgcn_mfma_f32_16x16x32_bf16(ah0, whi[kk], ahh0, 0, 0, 0);
        ahh1 = __builtin_amdgcn_mfma_f32_16x16x32_bf16(ah1, whi[kk], ahh1, 0, 0, 0);
        ahl0 = __builtin_amdgcn_mfma_f32_16x16x32_bf16(ah0, wlo[kk], ahl0, 0, 0, 0);
        ahl1 = __builtin_amdgcn_mfma_f32_16x16x32_bf16(ah1, wlo[kk], ahl1, 0, 0, 0);
        alh0 = __builtin_amdgcn_mfma_f32_16x16x32_bf16(al0, whi[kk], alh0, 0, 0, 0);
        alh1 = __builtin_amdgcn_mfma_f32_16x16x32_bf16(al1, whi[kk], alh1, 0, 0, 0);
      }
    }

    // scatter z_rec to LDS: row = (lane>>4)*4 + r, col = fr (m89 layout)
#pragma unroll
    for (int r = 0; r < 4; ++r) {
      zsh[g][(lane >> 4) * 4 + r][fr]      = ahh0[r] + ahl0[r] + alh0[r];
      zsh[g][16 + (lane >> 4) * 4 + r][fr] = ahh1[r] + ahl1[r] + alh1[r];
    }
    __syncthreads();

    // activation: 2 cells per thread (b = ab, ab+16), u = au
    float hn[2];
#pragma unroll
    for (int cc = 0; cc < 2; ++cc) {
      const int b = ab + cc * 16;
      const size_t zo = (size_t)(b * 64 + t) * 2048 + au;
      const float zi = zsh[0][b][uc] + zin[zo];
      const float zf = zsh[1][b][uc] + zin[zo + 512];
      const float zg = zsh[2][b][uc] + zin[zo + 1024];
      const float zz = zsh[3][b][uc] + zin[zo + 1536];
      const float i_ = 1.f / (1.f + expf(-zi));
      const float f_ = 1.f / (1.f + expf(-zf));
      const float g_ = tanhf(zg);
      const float o_ = 1.f / (1.f + expf(-zz));
      float& c = cc ? c1 : c0;
      c = f_ * c + i_ * g_;
      hn[cc] = o_ * tanhf(c);
      const float fm = jax_mask(2u, (uint32_t)((b * 64 + t) * 512 + au));
      rnn[(size_t)(b * 64 + t) * 512 + au] = f2bf(hn[cc] * fm);
    }

    // write masked h (hi + lo residual) for next step, opposite parity
    unsigned short* hw = hm + (size_t)(rp ^ 1) * HM_PSTRIDE;
#pragma unroll
    for (int cc = 0; cc < 2; ++cc) {
      const int b = ab + cc * 16;
#pragma unroll
      for (int gg = 0; gg < 4; ++gg) {
        const float v = hn[cc] * rmask[cc][gg];
        const unsigned short hb = f2bf(v);
        hw[(size_t)((0 * 4 + gg) * 32 + b) * 512 + au] = hb;
        hw[(size_t)((1 * 4 + gg) * 32 + b) * 512 + au] = f2bf(v - bf2f(hb));
      }
    }

    // grid-wide barrier: all blocks wrote step t's hm before anyone reads it
    grid_barrier(bar, (unsigned int)(NBLK * (t + 1)));
  }
}

// ---------------- launch -------------------------------------------------
extern "C" void kernel_launch(void* const* d_in, const int* in_sizes, int n_in,
                              void* d_out, int out_size, void* d_ws, size_t ws_size,
                              hipStream_t stream) {
  (void)in_sizes; (void)n_in; (void)out_size; (void)ws_size;
  const float* img   = (const float*)d_in[1];
  const int*   tgt   = (const int*)d_in[2];
  const float* emb   = (const float*)d_in[3];
  const float* W_in  = (const float*)d_in[4];
  const float* W_rec = (const float*)d_in[5];
  const float* b_l   = (const float*)d_in[6];
  const float* W_out = (const float*)d_in[7];
  const float* b_o   = (const float*)d_in[8];
  float* out = (float*)d_out;
  float* ws  = (float*)d_ws;

  float* zin = ws;                       // 4,194,304 f (16 MB)
  float* WT  = ws + 4194304;             // 1,048,576 f (4 MB)
  unsigned short* hm = (unsigned short*)(ws + 5242880);  // 2*HM_PSTRIDE us (512 KB)
  unsigned int* bar  = (unsigned int*)(ws + 5440000);    // grid barrier counter
  unsigned short* us = (unsigned short*)(ws + 5455872);
  unsigned short* x_bf  = us;            // 1,048,576 us (2 MB)
  unsigned short* WinT  = us + 1048576;  // 1,048,576 us
  unsigned short* rnn   = us + 2097152;  // 1,048,576 us
  unsigned short* WoutT = us + 3145728;  // 16,384,000 us (32.8 MB)

  hipMemsetAsync(bar, 0, 64, stream);    // reset barrier epoch counter

  build_x_kernel<<<4096, 256, 0, stream>>>(img, tgt, emb, x_bf);
  transpose_wrec<<<dim3(64, 16), 256, 0, stream>>>(W_rec, WT);
  transpose_cvt<<<dim3(64, 16), 256, 0, stream>>>(W_in, WinT, 512, 2048);
  transpose_cvt<<<dim3(1000, 16), 256, 0, stream>>>(W_out, WoutT, 512, 32000);

  // z_in = x @ W_in + b_lstm : (2048x512)@(512x2048), bf16 MFMA
  gemm_bf16_mfma<<<dim3(16, 16), 256, 0, stream>>>(x_bf, WinT, b_l, zin, 2048, 2048);

  // fused 64-step LSTM scan (persistent, hand-rolled grid barrier)
  lstm_coop<<<32, 256, 0, stream>>>(zin, WT, hm, rnn, bar);

  // predictions = rnn_out @ W_out + b_out : (2048x512)@(512x32000), bf16 MFMA
  gemm_bf16_mfma<<<dim3(250, 16), 256, 0, stream>>>(rnn, WoutT, b_o, out, 2048, 32000);
}